// Round 4
// baseline (2848.866 us; speedup 1.0000x reference)
//
#include <hip/hip_runtime.h>
#include <hip/hip_bf16.h>
#include <math.h>

#define HID 512
#define WCW_LD 576

typedef unsigned short u16;
typedef __attribute__((ext_vector_type(8))) short bf16x8;
typedef __attribute__((ext_vector_type(4))) float f32x4;

__device__ __forceinline__ u16 f2bf(float f) {
    union { float f; unsigned u; } x; x.f = f;
    unsigned r = x.u + 0x7fffu + ((x.u >> 16) & 1u);
    return (u16)(r >> 16);
}
__device__ __forceinline__ float bf2f(u16 b) {
    union { unsigned u; float f; } x; x.u = ((unsigned)b) << 16; return x.f;
}
__device__ __forceinline__ float sigm(float x) { return 1.f / (1.f + expf(-x)); }

// XOR swizzle within 128-B windows; valid for any row stride that is a
// multiple of 128 B. 16-B chunk-aligned reads stay contiguous.
__device__ __forceinline__ int swz(int row, int byte) { return byte ^ ((row & 7) << 4); }

// ---------------------------------------------------------------------------
// Pe[v][j] = emb[v].Wc_e[j] + Wc_b[j]  (fp32) ; PeT16 = bf16(tanh(Pe))
__global__ void pe_kernel(const float* __restrict__ emb, const float* __restrict__ Wc_w,
                          const float* __restrict__ Wc_b, float* __restrict__ Pe,
                          u16* __restrict__ PeT16) {
    int v = blockIdx.x, j = threadIdx.x;
    __shared__ float e[64];
    if (threadIdx.x < 64) e[threadIdx.x] = emb[v * 64 + threadIdx.x];
    __syncthreads();
    float acc = Wc_b[j];
    const float* w = Wc_w + (long long)j * WCW_LD;
#pragma unroll 8
    for (int k = 0; k < 64; ++k) acc += e[k] * w[k];
    Pe[v * HID + j] = acc;
    PeT16[v * HID + j] = f2bf(tanhf(acc));
}

__global__ void conv_w_kernel(const float* __restrict__ W_ih, const float* __restrict__ W_hh,
                              const float* __restrict__ Wc_w,
                              u16* __restrict__ Wih16, u16* __restrict__ Whh16,
                              u16* __restrict__ Wch16) {
    int idx = blockIdx.x * blockDim.x + threadIdx.x;
    int stride = gridDim.x * blockDim.x;
    for (int i = idx; i < 3 * HID * HID; i += stride) {
        Wih16[i] = f2bf(W_ih[i]);
        Whh16[i] = f2bf(W_hh[i]);
    }
    for (int i = idx; i < HID * HID; i += stride) {
        int j = i >> 9, k = i & 511;
        Wch16[i] = f2bf(Wc_w[(long long)j * WCW_LD + 64 + k]);
    }
}

// ---------------------------------------------------------------------------
// Gx = A @ Wih^T + b_ih  -> bf16 [M x 1536]. 128x64 tile, 4 waves.
// GATHER: A row m = PeT16[nt[4681+m]] (leaf level); else A row m = Asrc[m].
// grid: (24, ceil(M/128)) — j-index fastest so concurrent blocks share A.
template<bool GATHER>
__global__ __launch_bounds__(256)
void gx_gemm(const u16* __restrict__ Asrc, const u16* __restrict__ PeT16,
             const int* __restrict__ nt, const u16* __restrict__ Wih16,
             const float* __restrict__ b_ih, u16* __restrict__ gx16, int M) {
    __shared__ __align__(16) uint8_t sA[128 * 128];   // 128 rows x 64 bf16
    __shared__ __align__(16) uint8_t sB[64 * 128];
    int tid = threadIdx.x, lane = tid & 63, w = tid >> 6;
    int j0 = blockIdx.x * 64;
    int m0 = blockIdx.y * 128;

    f32x4 acc[2][4];
#pragma unroll
    for (int m = 0; m < 2; ++m)
#pragma unroll
        for (int jf = 0; jf < 4; ++jf) acc[m][jf] = (f32x4){0.f, 0.f, 0.f, 0.f};

    for (int k0 = 0; k0 < HID; k0 += 64) {
#pragma unroll
        for (int l = 0; l < 4; ++l) {
            int e = tid + l * 256;
            int r = e >> 3, c = e & 7;
            int gm = m0 + r;
            uint4 v = make_uint4(0u, 0u, 0u, 0u);
            if (gm < M) {
                const u16* src = GATHER ? (PeT16 + (long long)nt[4681 + gm] * HID)
                                        : (Asrc + (long long)gm * HID);
                v = *(const uint4*)(src + k0 + c * 8);
            }
            *(uint4*)(sA + r * 128 + swz(r, c * 16)) = v;
        }
#pragma unroll
        for (int l = 0; l < 2; ++l) {
            int e = tid + l * 256;
            int r = e >> 3, c = e & 7;
            uint4 v = *(const uint4*)(Wih16 + (long long)(j0 + r) * HID + k0 + c * 8);
            *(uint4*)(sB + r * 128 + swz(r, c * 16)) = v;
        }
        __syncthreads();
#pragma unroll
        for (int ks = 0; ks < 2; ++ks) {
            int kb = ks * 64 + ((lane >> 4) << 4);
            int ar = lane & 15;
            bf16x8 a0 = *(const bf16x8*)(sA + (w * 32 + ar) * 128 + swz(ar, kb));
            bf16x8 a1 = *(const bf16x8*)(sA + (w * 32 + 16 + ar) * 128 + swz(ar, kb));
#pragma unroll
            for (int jf = 0; jf < 4; ++jf) {
                bf16x8 b = *(const bf16x8*)(sB + (jf * 16 + ar) * 128 + swz(ar, kb));
                acc[0][jf] = __builtin_amdgcn_mfma_f32_16x16x32_bf16(a0, b, acc[0][jf], 0, 0, 0);
                acc[1][jf] = __builtin_amdgcn_mfma_f32_16x16x32_bf16(a1, b, acc[1][jf], 0, 0, 0);
            }
        }
        __syncthreads();
    }

#pragma unroll
    for (int jf = 0; jf < 4; ++jf) {
        int j = j0 + jf * 16 + (lane & 15);
        float bias = b_ih[j];
#pragma unroll
        for (int m = 0; m < 2; ++m) {
#pragma unroll
            for (int q = 0; q < 4; ++q) {
                int row = m0 + w * 32 + m * 16 + (lane >> 4) * 4 + q;
                if (row < M) gx16[(long long)row * 1536 + j] = f2bf(acc[m][jf][q] + bias);
            }
        }
    }
}

// ---------------------------------------------------------------------------
// Persistent level kernel: 8 GRU steps + combine, h in fp32 registers,
// per-step bf16 A-tile in double-buffered swizzled LDS, W_hh streamed from L2.
// Block: 256 threads (4 waves); wave w owns gate-columns [w*128, w*128+128).
// PP parents per block (PP in {32,16}); MT = PP/16 M-tiles.
template<int PP>
__global__ __launch_bounds__(256)
void gru_level(const u16* __restrict__ gx16, const u16* __restrict__ Whh16,
               const float* __restrict__ b_hh, const u16* __restrict__ Wch16,
               const int* __restrict__ nt, int off, const float* __restrict__ Pe,
               u16* __restrict__ enc16, float* __restrict__ outf, int n) {
    constexpr int MT = (PP + 15) / 16;
    constexpr int ROWS = MT * 16;
    __shared__ __align__(16) uint8_t At[2][ROWS * 1024];   // ROWS x 512 bf16, swizzled

    int tid = threadIdx.x, lane = tid & 63, w = tid >> 6;
    int p0 = blockIdx.x * PP;
    int nv = n - p0; if (nv > ROWS) nv = ROWS;   // valid rows in this block
    int jw = w * 128;                            // wave's gate-col base (0..511)
    int ar = lane & 15;                          // fragment row/col lane index
    int qr = lane >> 4;                          // quad index

    float h[MT][8][4];
#pragma unroll
    for (int m = 0; m < MT; ++m)
#pragma unroll
        for (int jt = 0; jt < 8; ++jt)
#pragma unroll
            for (int q = 0; q < 4; ++q) h[m][jt][q] = 0.f;

    // zero both A-tiles (rows >= nv must read as 0)
    for (int i = tid; i < 2 * ROWS * 1024 / 16; i += 256)
        ((uint4*)At)[i] = make_uint4(0u, 0u, 0u, 0u);
    __syncthreads();

    for (int t = 0; t < 8; ++t) {
        const uint8_t* Ac = At[t & 1];
        uint8_t* An = At[(t + 1) & 1];
#pragma unroll
        for (int jt = 0; jt < 8; ++jt) {
            int jcol = jw + jt * 16;
            f32x4 acc[3][MT];
#pragma unroll
            for (int g = 0; g < 3; ++g)
#pragma unroll
                for (int m = 0; m < MT; ++m) acc[g][m] = (f32x4){0.f, 0.f, 0.f, 0.f};

            if (t > 0) {
                const u16* brow0 = Whh16 + (long long)(jcol + ar) * HID + qr * 8;
                const u16* brow1 = brow0 + (long long)512 * HID;
                const u16* brow2 = brow1 + (long long)512 * HID;
#pragma unroll
                for (int kt = 0; kt < 16; ++kt) {
                    bf16x8 a[MT];
#pragma unroll
                    for (int m = 0; m < MT; ++m) {
                        int r = m * 16 + ar;
                        a[m] = *(const bf16x8*)(Ac + r * 1024 + swz(r, kt * 64 + qr * 16));
                    }
                    bf16x8 b0 = *(const bf16x8*)(brow0 + kt * 32);
                    bf16x8 b1 = *(const bf16x8*)(brow1 + kt * 32);
                    bf16x8 b2 = *(const bf16x8*)(brow2 + kt * 32);
#pragma unroll
                    for (int m = 0; m < MT; ++m) {
                        acc[0][m] = __builtin_amdgcn_mfma_f32_16x16x32_bf16(a[m], b0, acc[0][m], 0, 0, 0);
                        acc[1][m] = __builtin_amdgcn_mfma_f32_16x16x32_bf16(a[m], b1, acc[1][m], 0, 0, 0);
                        acc[2][m] = __builtin_amdgcn_mfma_f32_16x16x32_bf16(a[m], b2, acc[2][m], 0, 0, 0);
                    }
                }
            }
            // epilogue for this jt
            int j = jcol + ar;
            float bhr = b_hh[j], bhz = b_hh[HID + j], bhn = b_hh[2 * HID + j];
#pragma unroll
            for (int m = 0; m < MT; ++m) {
#pragma unroll
                for (int q = 0; q < 4; ++q) {
                    int r = m * 16 + qr * 4 + q;
                    float xr = 0.f, xz = 0.f, xn = 0.f;
                    if (r < nv) {
                        const u16* g0 = gx16 + (long long)((p0 + r) * 8 + t) * 1536 + j;
                        xr = bf2f(g0[0]); xz = bf2f(g0[512]); xn = bf2f(g0[1024]);
                    }
                    float rr = sigm(xr + acc[0][m][q] + bhr);
                    float zz = sigm(xz + acc[1][m][q] + bhz);
                    float cand = tanhf(xn + rr * (acc[2][m][q] + bhn));
                    float hnew = (1.f - zz) * cand + zz * h[m][jt][q];
                    h[m][jt][q] = hnew;
                    if (r < nv) *(u16*)(An + r * 1024 + swz(r, j * 2)) = f2bf(hnew);
                }
            }
        }
        __syncthreads();
    }

    // combine: A[0] holds final h (written at t=7). out = tanh(Pe[nt]+h.Wc_h^T)
    const uint8_t* Ac = At[0];
#pragma unroll
    for (int jt = 0; jt < 8; ++jt) {
        int jcol = jw + jt * 16;
        f32x4 acc[MT];
#pragma unroll
        for (int m = 0; m < MT; ++m) acc[m] = (f32x4){0.f, 0.f, 0.f, 0.f};
        const u16* brow = Wch16 + (long long)(jcol + ar) * HID + qr * 8;
#pragma unroll
        for (int kt = 0; kt < 16; ++kt) {
            bf16x8 b = *(const bf16x8*)(brow + kt * 32);
#pragma unroll
            for (int m = 0; m < MT; ++m) {
                int r = m * 16 + ar;
                bf16x8 a = *(const bf16x8*)(Ac + r * 1024 + swz(r, kt * 64 + qr * 16));
                acc[m] = __builtin_amdgcn_mfma_f32_16x16x32_bf16(a, b, acc[m], 0, 0, 0);
            }
        }
        int j = jcol + ar;
#pragma unroll
        for (int m = 0; m < MT; ++m) {
#pragma unroll
            for (int q = 0; q < 4; ++q) {
                int r = m * 16 + qr * 4 + q;
                if (r < nv) {
                    int p = p0 + r;
                    int tv = nt[off + p];
                    float v = tanhf(Pe[(long long)tv * HID + j] + acc[m][q]);
                    enc16[(long long)p * HID + j] = f2bf(v);
                    if (outf) outf[(long long)p * HID + j] = v;
                }
            }
        }
    }
}

// ---------------------------------------------------------------------------
extern "C" void kernel_launch(void* const* d_in, const int* in_sizes, int n_in,
                              void* d_out, int out_size, void* d_ws, size_t ws_size,
                              hipStream_t stream) {
    const int*   nt   = (const int*)d_in[0];
    const float* emb  = (const float*)d_in[1];
    const float* Wc_w = (const float*)d_in[2];
    const float* Wc_b = (const float*)d_in[3];
    const float* W_ih = (const float*)d_in[4];
    const float* W_hh = (const float*)d_in[5];
    const float* b_ih = (const float*)d_in[6];
    const float* b_hh = (const float*)d_in[7];

    uint8_t* p = (uint8_t*)d_ws;
    u16*   gx16  = (u16*)p;   p += (size_t)32768 * 1536 * 2;   // 96 MB
    u16*   enc16 = (u16*)p;   p += (size_t)4096 * HID * 2;     // 4 MB
    u16*   Wih16 = (u16*)p;   p += (size_t)3 * HID * HID * 2;
    u16*   Whh16 = (u16*)p;   p += (size_t)3 * HID * HID * 2;
    u16*   Wch16 = (u16*)p;   p += (size_t)HID * HID * 2;
    float* Pe    = (float*)p; p += (size_t)20 * HID * 4;
    u16*   PeT16 = (u16*)p;   p += (size_t)20 * HID * 2;

    conv_w_kernel<<<1024, 256, 0, stream>>>(W_ih, W_hh, Wc_w, Wih16, Whh16, Wch16);
    pe_kernel<<<20, 512, 0, stream>>>(emb, Wc_w, Wc_b, Pe, PeT16);

    const int sizes[5] = {1, 8, 64, 512, 4096};
    const int offs[5]  = {0, 1, 9, 73, 585};

    for (int d = 4; d >= 0; --d) {
        int n = sizes[d];
        int M = n * 8;
        dim3 ggrid(24, (M + 127) / 128);
        if (d == 4)
            gx_gemm<true><<<ggrid, 256, 0, stream>>>(nullptr, PeT16, nt, Wih16, b_ih, gx16, M);
        else
            gx_gemm<false><<<ggrid, 256, 0, stream>>>(enc16, nullptr, nt, Wih16, b_ih, gx16, M);

        float* outf = (d == 0) ? (float*)d_out : (float*)0;
        if (d == 4) {
            gru_level<32><<<128, 256, 0, stream>>>(gx16, Whh16, b_hh, Wch16, nt, offs[d],
                                                   Pe, enc16, outf, n);
        } else {
            int grid = (n + 15) / 16;
            gru_level<16><<<grid, 256, 0, stream>>>(gx16, Whh16, b_hh, Wch16, nt, offs[d],
                                                    Pe, enc16, outf, n);
        }
    }
}

// Round 5
// 1163.404 us; speedup vs baseline: 2.4487x; 2.4487x over previous
//
#include <hip/hip_runtime.h>
#include <hip/hip_bf16.h>
#include <math.h>

#define HID 512
#define WCW_LD 576

typedef unsigned short u16;
typedef __attribute__((ext_vector_type(8))) short bf16x8;
typedef __attribute__((ext_vector_type(4))) float f32x4;

__device__ __forceinline__ u16 f2bf(float f) {
    union { float f; unsigned u; } x; x.f = f;
    unsigned r = x.u + 0x7fffu + ((x.u >> 16) & 1u);
    return (u16)(r >> 16);
}
__device__ __forceinline__ float bf2f(u16 b) {
    union { unsigned u; float f; } x; x.u = ((unsigned)b) << 16; return x.f;
}
__device__ __forceinline__ float sigm(float x) { return 1.f / (1.f + expf(-x)); }

// XOR swizzle within 128-B windows (row stride multiple of 128 B)
__device__ __forceinline__ int swz(int row, int byte) { return byte ^ ((row & 7) << 4); }

// ---------------------------------------------------------------------------
// Pe[v][j] = emb[v].Wc_e[j] + Wc_b[j]  (fp32) ; PeT16 = bf16(tanh(Pe))
__global__ void pe_kernel(const float* __restrict__ emb, const float* __restrict__ Wc_w,
                          const float* __restrict__ Wc_b, float* __restrict__ Pe,
                          u16* __restrict__ PeT16) {
    int v = blockIdx.x, j = threadIdx.x;
    __shared__ float e[64];
    if (threadIdx.x < 64) e[threadIdx.x] = emb[v * 64 + threadIdx.x];
    __syncthreads();
    float acc = Wc_b[j];
    const float* w = Wc_w + (long long)j * WCW_LD;
#pragma unroll 8
    for (int k = 0; k < 64; ++k) acc += e[k] * w[k];
    Pe[v * HID + j] = acc;
    PeT16[v * HID + j] = f2bf(tanhf(acc));
}

__global__ void conv_w_kernel(const float* __restrict__ W_ih, const float* __restrict__ W_hh,
                              const float* __restrict__ Wc_w,
                              u16* __restrict__ Wih16, u16* __restrict__ Whh16,
                              u16* __restrict__ Wch16) {
    int idx = blockIdx.x * blockDim.x + threadIdx.x;
    int stride = gridDim.x * blockDim.x;
    for (int i = idx; i < 3 * HID * HID; i += stride) {
        Wih16[i] = f2bf(W_ih[i]);
        Whh16[i] = f2bf(W_hh[i]);
    }
    for (int i = idx; i < HID * HID; i += stride) {
        int j = i >> 9, k = i & 511;
        Wch16[i] = f2bf(Wc_w[(long long)j * WCW_LD + 64 + k]);
    }
}

// ---------------------------------------------------------------------------
// Gx = A @ Wih^T + b_ih  -> bf16 [M x 1536]. 128x64 tile, 4 waves.
// GATHER: A row m = PeT16[nt[4681+m]] (leaf fold); else A row m = Asrc[m].
// grid: (24, ceil(M/128)) — j fastest so concurrent blocks share A in L2.
template<bool GATHER>
__global__ __launch_bounds__(256)
void gx_gemm(const u16* __restrict__ Asrc, const u16* __restrict__ PeT16,
             const int* __restrict__ nt, const u16* __restrict__ Wih16,
             const float* __restrict__ b_ih, u16* __restrict__ gx16, int M) {
    __shared__ __align__(16) uint8_t sA[128 * 128];
    __shared__ __align__(16) uint8_t sB[64 * 128];
    int tid = threadIdx.x, lane = tid & 63, w = tid >> 6;
    int j0 = blockIdx.x * 64;
    int m0 = blockIdx.y * 128;

    f32x4 acc[2][4];
#pragma unroll
    for (int m = 0; m < 2; ++m)
#pragma unroll
        for (int jf = 0; jf < 4; ++jf) acc[m][jf] = (f32x4){0.f, 0.f, 0.f, 0.f};

    for (int k0 = 0; k0 < HID; k0 += 64) {
#pragma unroll
        for (int l = 0; l < 4; ++l) {
            int e = tid + l * 256;
            int r = e >> 3, c = e & 7;
            int gm = m0 + r;
            uint4 v = make_uint4(0u, 0u, 0u, 0u);
            if (gm < M) {
                const u16* src = GATHER ? (PeT16 + (long long)nt[4681 + gm] * HID)
                                        : (Asrc + (long long)gm * HID);
                v = *(const uint4*)(src + k0 + c * 8);
            }
            *(uint4*)(sA + r * 128 + swz(r, c * 16)) = v;
        }
#pragma unroll
        for (int l = 0; l < 2; ++l) {
            int e = tid + l * 256;
            int r = e >> 3, c = e & 7;
            uint4 v = *(const uint4*)(Wih16 + (long long)(j0 + r) * HID + k0 + c * 8);
            *(uint4*)(sB + r * 128 + swz(r, c * 16)) = v;
        }
        __syncthreads();
#pragma unroll
        for (int ks = 0; ks < 2; ++ks) {
            int kb = ks * 64 + ((lane >> 4) << 4);
            int ar = lane & 15;
            bf16x8 a0 = *(const bf16x8*)(sA + (w * 32 + ar) * 128 + swz(ar, kb));
            bf16x8 a1 = *(const bf16x8*)(sA + (w * 32 + 16 + ar) * 128 + swz(ar, kb));
#pragma unroll
            for (int jf = 0; jf < 4; ++jf) {
                bf16x8 b = *(const bf16x8*)(sB + (jf * 16 + ar) * 128 + swz(ar, kb));
                acc[0][jf] = __builtin_amdgcn_mfma_f32_16x16x32_bf16(a0, b, acc[0][jf], 0, 0, 0);
                acc[1][jf] = __builtin_amdgcn_mfma_f32_16x16x32_bf16(a1, b, acc[1][jf], 0, 0, 0);
            }
        }
        __syncthreads();
    }

#pragma unroll
    for (int jf = 0; jf < 4; ++jf) {
        int j = j0 + jf * 16 + (lane & 15);
        float bias = b_ih[j];
#pragma unroll
        for (int m = 0; m < 2; ++m) {
#pragma unroll
            for (int q = 0; q < 4; ++q) {
                int row = m0 + w * 32 + m * 16 + (lane >> 4) * 4 + q;
                if (row < M) gx16[(long long)row * 1536 + j] = f2bf(acc[m][jf][q] + bias);
            }
        }
    }
}

// ---------------------------------------------------------------------------
// h-side GRU step, MFMA (n >= 512): 3 gate GEMMs + update. 64x64 tile.
__global__ __launch_bounds__(256, 4)
void gru_step_h(const u16* __restrict__ gx16, int t,
                const float* __restrict__ hsrc_f, const u16* __restrict__ hsrc16,
                float* __restrict__ hdst_f, u16* __restrict__ hdst16,
                const u16* __restrict__ Whh16, const float* __restrict__ b_hh,
                int n, int has_h) {
    __shared__ __align__(16) uint8_t sm[4][8192];   // Ah, Bhh[3]
    int tid = threadIdx.x;
    int p0 = blockIdx.x * 64, j0 = blockIdx.y * 64;
    int lane = tid & 63, w = tid >> 6, wr = w >> 1, wc = w & 1;

    f32x4 acc[3][2][2];
#pragma unroll
    for (int g = 0; g < 3; ++g)
#pragma unroll
        for (int i = 0; i < 2; ++i)
#pragma unroll
            for (int j = 0; j < 2; ++j) acc[g][i][j] = (f32x4){0.f, 0.f, 0.f, 0.f};

    if (has_h) {
        for (int kt = 0; kt < 8; ++kt) {
            int k0 = kt * 64;
            // stage A (h) and 3 B tiles, swizzled
#pragma unroll
            for (int l = 0; l < 2; ++l) {
                int e = tid + l * 256;
                int r = e >> 3, c = e & 7;
                uint4 v = make_uint4(0u, 0u, 0u, 0u);
                if (p0 + r < n) v = *(const uint4*)(hsrc16 + (long long)(p0 + r) * HID + k0 + c * 8);
                *(uint4*)(sm[0] + r * 128 + swz(r, c * 16)) = v;
            }
#pragma unroll
            for (int g = 0; g < 3; ++g) {
#pragma unroll
                for (int l = 0; l < 2; ++l) {
                    int e = tid + l * 256;
                    int r = e >> 3, c = e & 7;
                    uint4 v = *(const uint4*)(Whh16 + (long long)(g * HID + j0 + r) * HID + k0 + c * 8);
                    *(uint4*)(sm[1 + g] + r * 128 + swz(r, c * 16)) = v;
                }
            }
            __syncthreads();
#pragma unroll
            for (int s = 0; s < 2; ++s) {
                int kb = s * 64 + ((lane >> 4) << 4);
                int ar = lane & 15;
                bf16x8 a0 = *(const bf16x8*)(sm[0] + (wr * 32 + ar) * 128 + swz(ar, kb));
                bf16x8 a1 = *(const bf16x8*)(sm[0] + (wr * 32 + 16 + ar) * 128 + swz(ar, kb));
#pragma unroll
                for (int g = 0; g < 3; ++g) {
#pragma unroll
                    for (int jf = 0; jf < 2; ++jf) {
                        bf16x8 b = *(const bf16x8*)(sm[1 + g] + (wc * 32 + jf * 16 + ar) * 128 + swz(ar, kb));
                        acc[g][0][jf] = __builtin_amdgcn_mfma_f32_16x16x32_bf16(a0, b, acc[g][0][jf], 0, 0, 0);
                        acc[g][1][jf] = __builtin_amdgcn_mfma_f32_16x16x32_bf16(a1, b, acc[g][1][jf], 0, 0, 0);
                    }
                }
            }
            __syncthreads();
        }
    }

#pragma unroll
    for (int i = 0; i < 2; ++i) {
#pragma unroll
        for (int jf = 0; jf < 2; ++jf) {
            int jj = j0 + wc * 32 + jf * 16 + (lane & 15);
            float bhr = b_hh[jj], bhz = b_hh[HID + jj], bhn = b_hh[2 * HID + jj];
#pragma unroll
            for (int q = 0; q < 4; ++q) {
                int p = p0 + wr * 32 + i * 16 + (lane >> 4) * 4 + q;
                if (p >= n) continue;
                long long gb = ((long long)(p * 8 + t)) * 1536 + jj;
                float xr = bf2f(gx16[gb]), xz = bf2f(gx16[gb + 512]), xn = bf2f(gx16[gb + 1024]);
                float r = sigm(xr + acc[0][i][jf][q] + bhr);
                float z = sigm(xz + acc[1][i][jf][q] + bhz);
                float cand = tanhf(xn + r * (acc[2][i][jf][q] + bhn));
                float hp = has_h ? hsrc_f[(long long)p * HID + jj] : 0.f;
                float hnew = (1.f - z) * cand + z * hp;
                hdst_f[(long long)p * HID + jj] = hnew;
                hdst16[(long long)p * HID + jj] = f2bf(hnew);
            }
        }
    }
}

// ---------------------------------------------------------------------------
// SIMT GRU step for small n (<= 64): one thread per (p, j). No LDS, no sync.
__global__ __launch_bounds__(256)
void gru_step_simt(const u16* __restrict__ gx16, int t,
                   const float* __restrict__ hsrc_f, const u16* __restrict__ hsrc16,
                   float* __restrict__ hdst_f, u16* __restrict__ hdst16,
                   const u16* __restrict__ Whh16, const float* __restrict__ b_hh,
                   int n, int has_h) {
    int idx = blockIdx.x * blockDim.x + threadIdx.x;
    int p = idx >> 9, j = idx & 511;
    if (p >= n) return;
    float a0 = 0.f, a1 = 0.f, a2 = 0.f;
    if (has_h) {
        const u16* hp = hsrc16 + (long long)p * HID;
        const u16* w0 = Whh16 + (long long)j * HID;
        const u16* w1 = w0 + (long long)HID * HID;
        const u16* w2 = w1 + (long long)HID * HID;
        for (int k = 0; k < HID; k += 8) {
            bf16x8 hv = *(const bf16x8*)(hp + k);
            bf16x8 v0 = *(const bf16x8*)(w0 + k);
            bf16x8 v1 = *(const bf16x8*)(w1 + k);
            bf16x8 v2 = *(const bf16x8*)(w2 + k);
#pragma unroll
            for (int i = 0; i < 8; ++i) {
                float hh = bf2f((u16)hv[i]);
                a0 += hh * bf2f((u16)v0[i]);
                a1 += hh * bf2f((u16)v1[i]);
                a2 += hh * bf2f((u16)v2[i]);
            }
        }
    }
    long long gb = ((long long)(p * 8 + t)) * 1536 + j;
    float xr = bf2f(gx16[gb]), xz = bf2f(gx16[gb + 512]), xn = bf2f(gx16[gb + 1024]);
    float r = sigm(xr + a0 + b_hh[j]);
    float z = sigm(xz + a1 + b_hh[HID + j]);
    float cand = tanhf(xn + r * (a2 + b_hh[2 * HID + j]));
    float hp_ = has_h ? hsrc_f[(long long)p * HID + j] : 0.f;
    float hnew = (1.f - z) * cand + z * hp_;
    hdst_f[(long long)p * HID + j] = hnew;
    hdst16[(long long)p * HID + j] = f2bf(hnew);
}

// ---------------------------------------------------------------------------
// SIMT combine for small n: out[p][j] = tanh(Pe[nt[off+p]][j] + h[p].Wc_h[j])
__global__ __launch_bounds__(256)
void combine_simt(const u16* __restrict__ h16, const u16* __restrict__ Wch16,
                  const int* __restrict__ nt, int off, const float* __restrict__ Pe,
                  u16* __restrict__ enc16, float* __restrict__ outf, int n) {
    int idx = blockIdx.x * blockDim.x + threadIdx.x;
    int p = idx >> 9, j = idx & 511;
    if (p >= n) return;
    float a = 0.f;
    const u16* hp = h16 + (long long)p * HID;
    const u16* wr = Wch16 + (long long)j * HID;
    for (int k = 0; k < HID; k += 8) {
        bf16x8 hv = *(const bf16x8*)(hp + k);
        bf16x8 wv = *(const bf16x8*)(wr + k);
#pragma unroll
        for (int i = 0; i < 8; ++i) a += bf2f((u16)hv[i]) * bf2f((u16)wv[i]);
    }
    int tv = nt[off + p];
    float v = tanhf(Pe[(long long)tv * HID + j] + a);
    enc16[(long long)p * HID + j] = f2bf(v);
    if (outf) outf[(long long)p * HID + j] = v;
}

// ---------------------------------------------------------------------------
// MFMA combine (n >= 512): enc16 = bf16(tanh(Pe[nt] + h @ Wc_h^T))
__global__ __launch_bounds__(256, 4)
void combine_mfma(const u16* __restrict__ enc_in, const u16* __restrict__ Wch16,
                  const int* __restrict__ nt, int off, const float* __restrict__ Pe,
                  u16* __restrict__ out16, int n) {
    __shared__ __align__(16) uint8_t sm[2][8192];
    int tid = threadIdx.x;
    int p0 = blockIdx.x * 64, j0 = blockIdx.y * 64;
    int lane = tid & 63, w = tid >> 6, wr = w >> 1, wc = w & 1;

    f32x4 acc[2][2];
#pragma unroll
    for (int i = 0; i < 2; ++i)
#pragma unroll
        for (int j = 0; j < 2; ++j) acc[i][j] = (f32x4){0.f, 0.f, 0.f, 0.f};

    for (int kt = 0; kt < 8; ++kt) {
        int k0 = kt * 64;
#pragma unroll
        for (int l = 0; l < 2; ++l) {
            int e = tid + l * 256;
            int r = e >> 3, c = e & 7;
            uint4 v = make_uint4(0u, 0u, 0u, 0u);
            if (p0 + r < n) v = *(const uint4*)(enc_in + (long long)(p0 + r) * HID + k0 + c * 8);
            *(uint4*)(sm[0] + r * 128 + swz(r, c * 16)) = v;
        }
#pragma unroll
        for (int l = 0; l < 2; ++l) {
            int e = tid + l * 256;
            int r = e >> 3, c = e & 7;
            uint4 v = *(const uint4*)(Wch16 + (long long)(j0 + r) * HID + k0 + c * 8);
            *(uint4*)(sm[1] + r * 128 + swz(r, c * 16)) = v;
        }
        __syncthreads();
#pragma unroll
        for (int s = 0; s < 2; ++s) {
            int kb = s * 64 + ((lane >> 4) << 4);
            int ar = lane & 15;
            bf16x8 a0 = *(const bf16x8*)(sm[0] + (wr * 32 + ar) * 128 + swz(ar, kb));
            bf16x8 a1 = *(const bf16x8*)(sm[0] + (wr * 32 + 16 + ar) * 128 + swz(ar, kb));
#pragma unroll
            for (int j = 0; j < 2; ++j) {
                bf16x8 b = *(const bf16x8*)(sm[1] + (wc * 32 + j * 16 + ar) * 128 + swz(ar, kb));
                acc[0][j] = __builtin_amdgcn_mfma_f32_16x16x32_bf16(a0, b, acc[0][j], 0, 0, 0);
                acc[1][j] = __builtin_amdgcn_mfma_f32_16x16x32_bf16(a1, b, acc[1][j], 0, 0, 0);
            }
        }
        __syncthreads();
    }

#pragma unroll
    for (int i = 0; i < 2; ++i) {
#pragma unroll
        for (int j = 0; j < 2; ++j) {
            int jj = j0 + wc * 32 + j * 16 + (lane & 15);
#pragma unroll
            for (int q = 0; q < 4; ++q) {
                int p = p0 + wr * 32 + i * 16 + (lane >> 4) * 4 + q;
                if (p >= n) continue;
                int tv = nt[off + p];
                float v = tanhf(Pe[(long long)tv * HID + jj] + acc[i][j][q]);
                out16[(long long)p * HID + jj] = f2bf(v);
            }
        }
    }
}

// ---------------------------------------------------------------------------
extern "C" void kernel_launch(void* const* d_in, const int* in_sizes, int n_in,
                              void* d_out, int out_size, void* d_ws, size_t ws_size,
                              hipStream_t stream) {
    const int*   nt   = (const int*)d_in[0];
    const float* emb  = (const float*)d_in[1];
    const float* Wc_w = (const float*)d_in[2];
    const float* Wc_b = (const float*)d_in[3];
    const float* W_ih = (const float*)d_in[4];
    const float* W_hh = (const float*)d_in[5];
    const float* b_ih = (const float*)d_in[6];
    const float* b_hh = (const float*)d_in[7];

    uint8_t* p = (uint8_t*)d_ws;
    u16*   gx16  = (u16*)p;   p += (size_t)32768 * 1536 * 2;   // 96 MB
    u16*   enc16 = (u16*)p;   p += (size_t)4096 * HID * 2;
    float* hwfA  = (float*)p; p += (size_t)4096 * HID * 4;
    float* hwfB  = (float*)p; p += (size_t)4096 * HID * 4;
    u16*   hw16A = (u16*)p;   p += (size_t)4096 * HID * 2;
    u16*   hw16B = (u16*)p;   p += (size_t)4096 * HID * 2;
    u16*   Wih16 = (u16*)p;   p += (size_t)3 * HID * HID * 2;
    u16*   Whh16 = (u16*)p;   p += (size_t)3 * HID * HID * 2;
    u16*   Wch16 = (u16*)p;   p += (size_t)HID * HID * 2;
    float* Pe    = (float*)p; p += (size_t)20 * HID * 4;
    u16*   PeT16 = (u16*)p;   p += (size_t)20 * HID * 2;

    conv_w_kernel<<<1024, 256, 0, stream>>>(W_ih, W_hh, Wc_w, Wih16, Whh16, Wch16);
    pe_kernel<<<20, 512, 0, stream>>>(emb, Wc_w, Wc_b, Pe, PeT16);

    const int sizes[5] = {1, 8, 64, 512, 4096};
    const int offs[5]  = {0, 1, 9, 73, 585};

    for (int d = 4; d >= 0; --d) {
        int n = sizes[d];
        int M = n * 8;
        dim3 ggrid(24, (M + 127) / 128);
        if (d == 4)
            gx_gemm<true><<<ggrid, 256, 0, stream>>>(nullptr, PeT16, nt, Wih16, b_ih, gx16, M);
        else
            gx_gemm<false><<<ggrid, 256, 0, stream>>>(enc16, nullptr, nt, Wih16, b_ih, gx16, M);

        if (n >= 512) {
            dim3 sgrid((n + 63) / 64, 8);
            for (int t = 0; t < 8; ++t) {
                const float* sf  = (t & 1) ? hwfA : hwfB;
                const u16*   s16 = (t & 1) ? hw16A : hw16B;
                float*       df  = (t & 1) ? hwfB : hwfA;
                u16*         d16 = (t & 1) ? hw16B : hw16A;
                gru_step_h<<<sgrid, 256, 0, stream>>>(gx16, t, sf, s16, df, d16,
                                                      Whh16, b_hh, n, t > 0);
            }
            combine_mfma<<<sgrid, 256, 0, stream>>>(hw16B, Wch16, nt, offs[d], Pe, enc16, n);
        } else {
            int blocks = n * 2;   // n*512 threads / 256
            for (int t = 0; t < 8; ++t) {
                const float* sf  = (t & 1) ? hwfA : hwfB;
                const u16*   s16 = (t & 1) ? hw16A : hw16B;
                float*       df  = (t & 1) ? hwfB : hwfA;
                u16*         d16 = (t & 1) ? hw16B : hw16A;
                gru_step_simt<<<blocks, 256, 0, stream>>>(gx16, t, sf, s16, df, d16,
                                                          Whh16, b_hh, n, t > 0);
            }
            combine_simt<<<blocks, 256, 0, stream>>>(hw16B, Wch16, nt, offs[d], Pe, enc16,
                                                     (d == 0) ? (float*)d_out : (float*)0, n);
        }
    }
}